// Round 1
// baseline (44.139 us; speedup 1.0000x reference)
//
#include <hip/hip_runtime.h>
#include <hip/hip_bf16.h>

// Row-wise L2 normalization: x[i,:] / max(||x[i,:]||_2, guarded at 0 -> 1)
// Rows are 4 f32 -> exactly one float4 per row. Pure streaming, memory-bound.
// One thread handles one (or more, grid-strided) rows: float4 load, 3 FMA,
// rsqrt, 4 mul, float4 store. 16 B/lane coalesced both directions.

__global__ void __launch_bounds__(256)
l2norm_rows_kernel(const float4* __restrict__ x, float4* __restrict__ out, int nrows) {
    int stride = gridDim.x * blockDim.x;
    for (int i = blockIdx.x * blockDim.x + threadIdx.x; i < nrows; i += stride) {
        float4 v = x[i];
        float s = v.x * v.x + v.y * v.y + v.z * v.z + v.w * v.w;
        // zero-norm rows pass through unchanged (scale = 1)
        float inv = (s > 0.0f) ? rsqrtf(s) : 1.0f;
        float4 o;
        o.x = v.x * inv;
        o.y = v.y * inv;
        o.z = v.z * inv;
        o.w = v.w * inv;
        out[i] = o;
    }
}

extern "C" void kernel_launch(void* const* d_in, const int* in_sizes, int n_in,
                              void* d_out, int out_size, void* d_ws, size_t ws_size,
                              hipStream_t stream) {
    const float4* x = (const float4*)d_in[0];
    float4* out = (float4*)d_out;
    int nrows = in_sizes[0] / 4;   // flat element count / 4 elems per row

    const int block = 256;
    int grid = (nrows + block - 1) / block;
    if (grid > 4096) grid = 4096;   // grid-stride the rest
    l2norm_rows_kernel<<<grid, block, 0, stream>>>(x, out, nrows);
}